// Round 1
// baseline (422.184 us; speedup 1.0000x reference)
//
#include <hip/hip_runtime.h>

#define BB 4
#define CC 96
#define NN 3136
#define FLTMAX 3.402823466e+38f

// ---------------- K2: Mw (384x96): rows 0..191 = W1-W2, rows 192..383 = W2 ----
__global__ __launch_bounds__(256) void k_mw(const float* __restrict__ gw, float* __restrict__ Mw) {
    int i = blockIdx.x * 256 + threadIdx.x;
    if (i >= 384 * 96) return;
    int o = i / 96, c = i - o * 96;
    float v;
    if (o < 192) v = gw[o * 192 + c] - gw[o * 192 + 96 + c];
    else         v = gw[(o - 192) * 192 + 96 + c];
    Mw[i] = v;
}

// ---------------- K1: fc1 -> h (b,c,n) + x2 ----------------------------------
__global__ __launch_bounds__(256) void k_fc1(const float* __restrict__ x, const float* __restrict__ w,
                                             const float* __restrict__ bias, float* __restrict__ h,
                                             float* __restrict__ x2g) {
    __shared__ float sm[96 * 98 + 96 * 64];
    float* wT = sm;              // [c][o] pad 98
    float* xl = sm + 96 * 98;    // [c][64]
    const int tid = threadIdx.x;
    const int n0 = blockIdx.x * 64;
    const int b = blockIdx.y;
    for (int i = tid; i < 96 * 96; i += 256) {
        int o = i / 96, c = i - o * 96;
        wT[c * 98 + o] = w[i];
    }
    const float* xb = x + (size_t)b * CC * NN;
    for (int i = tid; i < 96 * 64; i += 256) {
        int c = i >> 6, nl = i & 63;
        xl[i] = xb[(size_t)c * NN + n0 + nl];
    }
    __syncthreads();
    const int tr = tid >> 4, tc = tid & 15;
    float acc[6][4];
#pragma unroll
    for (int i = 0; i < 6; ++i)
#pragma unroll
        for (int j = 0; j < 4; ++j) acc[i][j] = 0.f;
#pragma unroll 4
    for (int c = 0; c < 96; ++c) {
        float4 xv = *(const float4*)&xl[c * 64 + tc * 4];
        const float* wp = &wT[c * 98 + tr * 6];
        float2 w01 = *(const float2*)(wp);
        float2 w23 = *(const float2*)(wp + 2);
        float2 w45 = *(const float2*)(wp + 4);
        float wv[6] = {w01.x, w01.y, w23.x, w23.y, w45.x, w45.y};
        float xj[4] = {xv.x, xv.y, xv.z, xv.w};
#pragma unroll
        for (int i = 0; i < 6; ++i)
#pragma unroll
            for (int j = 0; j < 4; ++j) acc[i][j] = fmaf(wv[i], xj[j], acc[i][j]);
    }
    float* hb = h + (size_t)b * CC * NN;
#pragma unroll
    for (int i = 0; i < 6; ++i) {
        float bi = bias[tr * 6 + i];
        acc[i][0] += bi; acc[i][1] += bi; acc[i][2] += bi; acc[i][3] += bi;
        float4 o4 = make_float4(acc[i][0], acc[i][1], acc[i][2], acc[i][3]);
        *(float4*)&hb[(size_t)(tr * 6 + i) * NN + n0 + tc * 4] = o4;
    }
    __syncthreads();   // wT/xl reads done -> reuse sm[0..1024) for x2 partials
#pragma unroll
    for (int j = 0; j < 4; ++j) {
        float s = 0.f;
#pragma unroll
        for (int i = 0; i < 6; ++i) s = fmaf(acc[i][j], acc[i][j], s);
        sm[tr * 64 + tc * 4 + j] = s;
    }
    __syncthreads();
    if (tid < 64) {
        float s = 0.f;
#pragma unroll
        for (int t = 0; t < 16; ++t) s += sm[t * 64 + tid];
        x2g[(size_t)b * NN + n0 + tid] = s;
    }
}

// ---------------- K3: fused distance + per-split top-9 -----------------------
// grid (49 row-tiles, 8 splits, B). score = x2[m] - 2*inner[n,m]
__global__ __launch_bounds__(256) void k_dist(const float* __restrict__ h, const float* __restrict__ x2,
                                              float* __restrict__ cand_val, int* __restrict__ cand_idx) {
    __shared__ float hn[96 * 64];   // rows tile (persistent)
    __shared__ float hm[48 * 64];   // cols tile, half channels
    __shared__ float sc[64 * 65];   // score tile (pad 65)
    const int tid = threadIdx.x;
    const int nt = blockIdx.x, s = blockIdx.y, b = blockIdx.z;
    const int n0 = nt * 64;
    const float* hb = h + (size_t)b * CC * NN;
    for (int i = tid; i < 96 * 64; i += 256) {
        int c = i >> 6, nl = i & 63;
        hn[i] = hb[(size_t)c * NN + n0 + nl];
    }
    float vals[9]; int inds[9];
#pragma unroll
    for (int k = 0; k < 9; ++k) { vals[k] = FLTMAX; inds[k] = 0x7fffffff; }
    float vmax = FLTMAX; int smax = 0;
    const int tr = tid >> 4, tc = tid & 15;
    const int row = tid & 63, q = tid >> 6;
    __syncthreads();

    for (int t = s; t < 49; t += 8) {
        const int m0 = t * 64;
        float acc[4][4];
#pragma unroll
        for (int i = 0; i < 4; ++i)
#pragma unroll
            for (int j = 0; j < 4; ++j) acc[i][j] = 0.f;
        // chunk 0: channels 0..47
        for (int i = tid; i < 48 * 64; i += 256) {
            int c = i >> 6, ml = i & 63;
            hm[i] = hb[(size_t)c * NN + m0 + ml];
        }
        __syncthreads();
#pragma unroll 6
        for (int c = 0; c < 48; ++c) {
            float4 av = *(const float4*)&hn[c * 64 + tr * 4];
            float4 bv = *(const float4*)&hm[c * 64 + tc * 4];
            float a4[4] = {av.x, av.y, av.z, av.w};
            float b4[4] = {bv.x, bv.y, bv.z, bv.w};
#pragma unroll
            for (int i = 0; i < 4; ++i)
#pragma unroll
                for (int j = 0; j < 4; ++j) acc[i][j] = fmaf(a4[i], b4[j], acc[i][j]);
        }
        __syncthreads();
        // chunk 1: channels 48..95
        for (int i = tid; i < 48 * 64; i += 256) {
            int c = i >> 6, ml = i & 63;
            hm[i] = hb[(size_t)(48 + c) * NN + m0 + ml];
        }
        __syncthreads();
#pragma unroll 6
        for (int c = 0; c < 48; ++c) {
            float4 av = *(const float4*)&hn[(48 + c) * 64 + tr * 4];
            float4 bv = *(const float4*)&hm[c * 64 + tc * 4];
            float a4[4] = {av.x, av.y, av.z, av.w};
            float b4[4] = {bv.x, bv.y, bv.z, bv.w};
#pragma unroll
            for (int i = 0; i < 4; ++i)
#pragma unroll
                for (int j = 0; j < 4; ++j) acc[i][j] = fmaf(a4[i], b4[j], acc[i][j]);
        }
        float4 x2v = *(const float4*)&x2[(size_t)b * NN + m0 + tc * 4];
        float x2a[4] = {x2v.x, x2v.y, x2v.z, x2v.w};
#pragma unroll
        for (int i = 0; i < 4; ++i)
#pragma unroll
            for (int j = 0; j < 4; ++j)
                sc[(tr * 4 + i) * 65 + tc * 4 + j] = fmaf(-2.f, acc[i][j], x2a[j]);
        __syncthreads();
        // scan: thread (row, q) scans its 16 columns, maintains top-9
#pragma unroll
        for (int tt = 0; tt < 16; ++tt) {
            float v = sc[row * 65 + q * 16 + tt];
            if (v < vmax) {
                int m = m0 + q * 16 + tt;
#pragma unroll
                for (int k = 0; k < 9; ++k)
                    if (k == smax) { vals[k] = v; inds[k] = m; }
                vmax = vals[0]; smax = 0;
#pragma unroll
                for (int k = 1; k < 9; ++k)
                    if (vals[k] > vmax) { vmax = vals[k]; smax = k; }
            }
        }
        __syncthreads();
    }
    // merge 4 quarters per row -> per-split top-9 (reuse hn as scratch)
    float* mbv = hn;
    int* mbi = (int*)(hn + 64 * 36);
#pragma unroll
    for (int k = 0; k < 9; ++k) {
        mbv[row * 36 + q * 9 + k] = vals[k];
        mbi[row * 36 + q * 9 + k] = inds[k];
    }
    __syncthreads();
    if (tid < 64) {
        size_t gbase = (size_t)b * NN + n0 + tid;
        for (int kk = 0; kk < 9; ++kk) {
            float bv = FLTMAX; int bi = 0x7fffffff; int bs = 0;
            for (int j = 0; j < 36; ++j) {
                float v = mbv[tid * 36 + j]; int ii = mbi[tid * 36 + j];
                if (v < bv || (v == bv && ii < bi)) { bv = v; bi = ii; bs = j; }
            }
            mbv[tid * 36 + bs] = FLTMAX;
            cand_val[(size_t)(s * 9 + kk) * (BB * NN) + gbase] = bv;
            cand_idx[(size_t)(s * 9 + kk) * (BB * NN) + gbase] = bi;
        }
    }
}

// ---------------- K4: merge 8 splits -> idx9 ---------------------------------
__global__ __launch_bounds__(256) void k_merge(const float* __restrict__ cand_val,
                                               const int* __restrict__ cand_idx,
                                               int* __restrict__ idx9) {
    int gid = blockIdx.x * 256 + threadIdx.x;   // exactly B*N
    float vals[9]; int inds[9];
#pragma unroll
    for (int k = 0; k < 9; ++k) { vals[k] = FLTMAX; inds[k] = 0x7fffffff; }
    float vmax = FLTMAX; int smax = 0;
    for (int j = 0; j < 72; ++j) {
        float v = cand_val[(size_t)j * (BB * NN) + gid];
        int ii = cand_idx[(size_t)j * (BB * NN) + gid];
        if (v < vmax) {
#pragma unroll
            for (int k = 0; k < 9; ++k)
                if (k == smax) { vals[k] = v; inds[k] = ii; }
            vmax = vals[0]; smax = 0;
#pragma unroll
            for (int k = 1; k < 9; ++k)
                if (vals[k] > vmax) { vmax = vals[k]; smax = k; }
        }
    }
#pragma unroll
    for (int k = 0; k < 9; ++k) idx9[(size_t)gid * 9 + k] = inds[k];
}

// ---------------- K5: [U;V] @ h -> acT (b,n,384), U-part with bias -----------
__global__ __launch_bounds__(256) void k_ac(const float* __restrict__ h, const float* __restrict__ Mw,
                                            const float* __restrict__ gb, float* __restrict__ acT) {
    __shared__ float sm[96 * 98 + 96 * 64];
    float* wT = sm;
    float* hl = sm + 96 * 98;
    const int tid = threadIdx.x;
    const int n0 = blockIdx.x * 64, ot = blockIdx.y, b = blockIdx.z;
    for (int i = tid; i < 96 * 96; i += 256) {
        int o = i / 96, c = i - o * 96;
        wT[c * 98 + o] = Mw[(size_t)(ot * 96 + o) * 96 + c];
    }
    const float* hb = h + (size_t)b * CC * NN;
    for (int i = tid; i < 96 * 64; i += 256) {
        int c = i >> 6, nl = i & 63;
        hl[i] = hb[(size_t)c * NN + n0 + nl];
    }
    __syncthreads();
    const int tr = tid >> 4, tc = tid & 15;
    float acc[6][4];
#pragma unroll
    for (int i = 0; i < 6; ++i)
#pragma unroll
        for (int j = 0; j < 4; ++j) acc[i][j] = 0.f;
#pragma unroll 4
    for (int c = 0; c < 96; ++c) {
        float4 xv = *(const float4*)&hl[c * 64 + tc * 4];
        const float* wp = &wT[c * 98 + tr * 6];
        float2 w01 = *(const float2*)(wp);
        float2 w23 = *(const float2*)(wp + 2);
        float2 w45 = *(const float2*)(wp + 4);
        float wv[6] = {w01.x, w01.y, w23.x, w23.y, w45.x, w45.y};
        float xj[4] = {xv.x, xv.y, xv.z, xv.w};
#pragma unroll
        for (int i = 0; i < 6; ++i)
#pragma unroll
            for (int j = 0; j < 4; ++j) acc[i][j] = fmaf(wv[i], xj[j], acc[i][j]);
    }
    const int obase = ot * 96 + tr * 6;
    float bs[6];
#pragma unroll
    for (int i = 0; i < 6; ++i) bs[i] = (ot < 2) ? gb[obase + i] : 0.f;
#pragma unroll
    for (int j = 0; j < 4; ++j) {
        float* dst = acT + ((size_t)b * NN + n0 + tc * 4 + j) * 384 + obase;
        *(float2*)(dst + 0) = make_float2(acc[0][j] + bs[0], acc[1][j] + bs[1]);
        *(float2*)(dst + 2) = make_float2(acc[2][j] + bs[2], acc[3][j] + bs[3]);
        *(float2*)(dst + 4) = make_float2(acc[4][j] + bs[4], acc[5][j] + bs[5]);
    }
}

// ---------------- K6: gather neighbors, k-max, relu -> gT (b,n,192) ----------
__global__ __launch_bounds__(64) void k_gather(const float* __restrict__ acT, const int* __restrict__ idx9,
                                               float* __restrict__ gT) {
    const int lane = threadIdx.x;
    const int b = blockIdx.y;
    const int nb = blockIdx.x * 4;
    for (int r = 0; r < 4; ++r) {
        const int n = nb + r;
        const float* ar = acT + ((size_t)b * NN + n) * 384;
        float a0 = ar[lane], a1 = ar[lane + 64], a2 = ar[lane + 128];
        const int* ip = idx9 + ((size_t)b * NN + n) * 9;
        int jj[9];
#pragma unroll
        for (int k = 0; k < 9; ++k) jj[k] = ip[k];
        float m0 = -FLTMAX, m1 = -FLTMAX, m2 = -FLTMAX;
#pragma unroll
        for (int k = 0; k < 9; ++k) {
            const float* cr = acT + ((size_t)b * NN + jj[k]) * 384 + 192;
            m0 = fmaxf(m0, a0 + cr[lane]);
            m1 = fmaxf(m1, a1 + cr[lane + 64]);
            m2 = fmaxf(m2, a2 + cr[lane + 128]);
        }
        float* gr = gT + ((size_t)b * NN + n) * 192;
        gr[lane] = fmaxf(m0, 0.f);
        gr[lane + 64] = fmaxf(m1, 0.f);
        gr[lane + 128] = fmaxf(m2, 0.f);
    }
}

// ---------------- K7: fc2 (NT gemm) -> out (b,c,n) ---------------------------
__global__ __launch_bounds__(256) void k_fc2(const float* __restrict__ gT, const float* __restrict__ w,
                                             const float* __restrict__ bias, float* __restrict__ out) {
    __shared__ float Wc[96 * 36];
    __shared__ float Gc[64 * 36];
    const int tid = threadIdx.x;
    const int n0 = blockIdx.x * 64, b = blockIdx.y;
    const int tr = tid >> 4, tc = tid & 15;
    float acc[6][4];
#pragma unroll
    for (int i = 0; i < 6; ++i)
#pragma unroll
        for (int j = 0; j < 4; ++j) acc[i][j] = 0.f;
    for (int kc = 0; kc < 192; kc += 32) {
        for (int i = tid; i < 96 * 32; i += 256) {
            int c = i >> 5, k = i & 31;
            Wc[c * 36 + k] = w[(size_t)c * 192 + kc + k];
        }
        for (int i = tid; i < 64 * 32; i += 256) {
            int nl = i >> 5, k = i & 31;
            Gc[nl * 36 + k] = gT[((size_t)b * NN + n0 + nl) * 192 + kc + k];
        }
        __syncthreads();
#pragma unroll
        for (int k = 0; k < 32; k += 4) {
            float4 wv[6]; float4 gv[4];
#pragma unroll
            for (int i = 0; i < 6; ++i) wv[i] = *(const float4*)&Wc[(tr * 6 + i) * 36 + k];
#pragma unroll
            for (int j = 0; j < 4; ++j) gv[j] = *(const float4*)&Gc[(tc * 4 + j) * 36 + k];
#pragma unroll
            for (int i = 0; i < 6; ++i)
#pragma unroll
                for (int j = 0; j < 4; ++j) {
                    acc[i][j] = fmaf(wv[i].x, gv[j].x, acc[i][j]);
                    acc[i][j] = fmaf(wv[i].y, gv[j].y, acc[i][j]);
                    acc[i][j] = fmaf(wv[i].z, gv[j].z, acc[i][j]);
                    acc[i][j] = fmaf(wv[i].w, gv[j].w, acc[i][j]);
                }
        }
        __syncthreads();
    }
    float* ob = out + (size_t)b * CC * NN;
#pragma unroll
    for (int i = 0; i < 6; ++i) {
        float bi = bias[tr * 6 + i];
        float4 o4 = make_float4(acc[i][0] + bi, acc[i][1] + bi, acc[i][2] + bi, acc[i][3] + bi);
        *(float4*)&ob[(size_t)(tr * 6 + i) * NN + n0 + tc * 4] = o4;
    }
}

// ---------------- K8: channel mean/max -> sa_in (b,2,n) ----------------------
__global__ __launch_bounds__(256) void k_stats(const float* __restrict__ out, float* __restrict__ sa_in) {
    int n = blockIdx.x * 256 + threadIdx.x;
    int b = blockIdx.y;
    if (n >= NN) return;
    const float* ob = out + (size_t)b * CC * NN + n;
    float s = 0.f, mx = -FLTMAX;
#pragma unroll 8
    for (int c = 0; c < 96; ++c) {
        float v = ob[(size_t)c * NN];
        s += v;
        mx = fmaxf(mx, v);
    }
    sa_in[(size_t)b * 2 * NN + n] = s * (1.0f / 96.0f);
    sa_in[(size_t)b * 2 * NN + NN + n] = mx;
}

// ---------------- K9: 7x7 conv + sigmoid + out*att + shortcut (in place) -----
__global__ __launch_bounds__(256) void k_att(const float* __restrict__ sa_in, const float* __restrict__ sw,
                                             const float* __restrict__ x, float* __restrict__ out) {
    int n = blockIdx.x * 256 + threadIdx.x;
    int b = blockIdx.y;
    if (n >= NN) return;
    int y = n / 56, xw = n - y * 56;
    float acc = 0.f;
#pragma unroll
    for (int ci = 0; ci < 2; ++ci) {
        const float* sb = sa_in + ((size_t)b * 2 + ci) * NN;
#pragma unroll
        for (int dy = 0; dy < 7; ++dy) {
            int yy = y + dy - 3;
            if ((unsigned)yy < 56u) {
#pragma unroll
                for (int dx = 0; dx < 7; ++dx) {
                    int xx = xw + dx - 3;
                    if ((unsigned)xx < 56u)
                        acc = fmaf(sb[yy * 56 + xx], sw[(ci * 7 + dy) * 7 + dx], acc);
                }
            }
        }
    }
    float att = 1.f / (1.f + expf(-acc));
    const float* xb = x + (size_t)b * CC * NN + n;
    float* ob = out + (size_t)b * CC * NN + n;
#pragma unroll 4
    for (int c = 0; c < 96; ++c) {
        size_t o = (size_t)c * NN;
        ob[o] = fmaf(ob[o], att, xb[o]);
    }
}

extern "C" void kernel_launch(void* const* d_in, const int* in_sizes, int n_in,
                              void* d_out, int out_size, void* d_ws, size_t ws_size,
                              hipStream_t stream) {
    (void)in_sizes; (void)n_in; (void)out_size; (void)ws_size;
    const float* x       = (const float*)d_in[0];
    const float* fc1_w   = (const float*)d_in[1];
    const float* fc1_b   = (const float*)d_in[2];
    const float* gconv_w = (const float*)d_in[3];
    const float* gconv_b = (const float*)d_in[4];
    const float* fc2_w   = (const float*)d_in[5];
    const float* fc2_b   = (const float*)d_in[6];
    const float* sa_w    = (const float*)d_in[7];
    float* out = (float*)d_out;

    // workspace layout (floats); cand_* alias gT region (disjoint lifetimes)
    float* ws   = (float*)d_ws;
    float* h    = ws;                                   // 1,204,224
    float* Mw   = h + (size_t)BB * CC * NN;             // 36,864
    float* x2   = Mw + 384 * 96;                        // 12,544
    int*   idx9 = (int*)(x2 + BB * NN);                 // 112,896 ints
    float* acT  = (float*)(idx9 + (size_t)BB * NN * 9); // 4,816,896
    float* gT   = acT + (size_t)BB * NN * 384;          // 2,408,448
    float* cand_val = gT;                               // 903,168 (aliases gT)
    int*   cand_idx = (int*)(cand_val + (size_t)72 * BB * NN);
    float* sa_in = gT + (size_t)BB * NN * 192;          // 25,088

    k_mw    <<<dim3(144), 256, 0, stream>>>(gconv_w, Mw);
    k_fc1   <<<dim3(49, BB), 256, 0, stream>>>(x, fc1_w, fc1_b, h, x2);
    k_dist  <<<dim3(49, 8, BB), 256, 0, stream>>>(h, x2, cand_val, cand_idx);
    k_merge <<<dim3(49), 256, 0, stream>>>(cand_val, cand_idx, idx9);
    k_ac    <<<dim3(49, 4, BB), 256, 0, stream>>>(h, Mw, gconv_b, acT);
    k_gather<<<dim3(784, BB), 64, 0, stream>>>(acT, idx9, gT);
    k_fc2   <<<dim3(49, BB), 256, 0, stream>>>(gT, fc2_w, fc2_b, out);
    k_stats <<<dim3(13, BB), 256, 0, stream>>>(out, sa_in);
    k_att   <<<dim3(13, BB), 256, 0, stream>>>(sa_in, sa_w, x, out);
}

// Round 2
// 397.998 us; speedup vs baseline: 1.0608x; 1.0608x over previous
//
#include <hip/hip_runtime.h>

#define BB 4
#define CC 96
#define NN 3136
#define FLTMAX 3.402823466e+38f

typedef const __attribute__((address_space(1))) void* gas_p;
typedef __attribute__((address_space(3))) void* las_p;

__device__ __forceinline__ void gload_lds16(const float* g, float* l) {
    __builtin_amdgcn_global_load_lds((gas_p)g, (las_p)l, 16, 0, 0);
}

// ---------------- K1: fc1 -> h (b,c,n) + x2 ----------------------------------
__global__ __launch_bounds__(256) void k_fc1(const float* __restrict__ x, const float* __restrict__ w,
                                             const float* __restrict__ bias, float* __restrict__ h,
                                             float* __restrict__ x2g) {
    __shared__ float sm[96 * 98 + 96 * 64];
    float* wT = sm;              // [c][o] pad 98
    float* xl = sm + 96 * 98;    // [c][64]
    const int tid = threadIdx.x;
    const int n0 = blockIdx.x * 64;
    const int b = blockIdx.y;
    for (int i = tid; i < 96 * 96; i += 256) {
        int o = i / 96, c = i - o * 96;
        wT[c * 98 + o] = w[i];
    }
    const float* xb = x + (size_t)b * CC * NN;
    for (int i = tid; i < 96 * 64; i += 256) {
        int c = i >> 6, nl = i & 63;
        xl[i] = xb[(size_t)c * NN + n0 + nl];
    }
    __syncthreads();
    const int tr = tid >> 4, tc = tid & 15;
    float acc[6][4];
#pragma unroll
    for (int i = 0; i < 6; ++i)
#pragma unroll
        for (int j = 0; j < 4; ++j) acc[i][j] = 0.f;
#pragma unroll 4
    for (int c = 0; c < 96; ++c) {
        float4 xv = *(const float4*)&xl[c * 64 + tc * 4];
        const float* wp = &wT[c * 98 + tr * 6];
        float2 w01 = *(const float2*)(wp);
        float2 w23 = *(const float2*)(wp + 2);
        float2 w45 = *(const float2*)(wp + 4);
        float wv[6] = {w01.x, w01.y, w23.x, w23.y, w45.x, w45.y};
        float xj[4] = {xv.x, xv.y, xv.z, xv.w};
#pragma unroll
        for (int i = 0; i < 6; ++i)
#pragma unroll
            for (int j = 0; j < 4; ++j) acc[i][j] = fmaf(wv[i], xj[j], acc[i][j]);
    }
    float* hb = h + (size_t)b * CC * NN;
#pragma unroll
    for (int i = 0; i < 6; ++i) {
        float bi = bias[tr * 6 + i];
        acc[i][0] += bi; acc[i][1] += bi; acc[i][2] += bi; acc[i][3] += bi;
        float4 o4 = make_float4(acc[i][0], acc[i][1], acc[i][2], acc[i][3]);
        *(float4*)&hb[(size_t)(tr * 6 + i) * NN + n0 + tc * 4] = o4;
    }
    __syncthreads();   // wT/xl reads done -> reuse sm[0..1024) for x2 partials
#pragma unroll
    for (int j = 0; j < 4; ++j) {
        float s = 0.f;
#pragma unroll
        for (int i = 0; i < 6; ++i) s = fmaf(acc[i][j], acc[i][j], s);
        sm[tr * 64 + tc * 4 + j] = s;
    }
    __syncthreads();
    if (tid < 64) {
        float s = 0.f;
#pragma unroll
        for (int t = 0; t < 16; ++t) s += sm[t * 64 + tid];
        x2g[(size_t)b * NN + n0 + tid] = s;
    }
}

// ---------------- K3: fused distance + per-split top-9 (register lists) ------
// grid (49 row-tiles, 8 splits, B). score = x2[m] - 2*inner[n,m]
// thread owns rows {trr*2, trr*2+1} x cols {tc8..tc8+7} of the 64x64 tile.
__global__ __launch_bounds__(256, 3) void k_dist(const float* __restrict__ h,
                                                 const float* __restrict__ x2,
                                                 float* __restrict__ cand_val,
                                                 int* __restrict__ cand_idx) {
    __shared__ __align__(16) float smem[96 * 64 + 48 * 64];   // 36 KB
    float* hn = smem;             // [96][64] row tile
    float* hm = smem + 96 * 64;   // [48][64] col tile (channel chunk)
    const int tid = threadIdx.x;
    const int nt = blockIdx.x, s = blockIdx.y, b = blockIdx.z;
    const int n0 = nt * 64;
    const int lane = tid & 63, w = tid >> 6;
    const int lrow = lane >> 4, lcol = (lane & 15) * 4;
    const float* hb = h + (size_t)b * CC * NN;

    // async stage hn: wave w stages channel rows [24w, 24w+24)
    {
        const float* g = hb + (size_t)(w * 24 + lrow) * NN + n0 + lcol;
#pragma unroll
        for (int j = 0; j < 6; ++j)
            gload_lds16(g + (size_t)(4 * j) * NN, hn + (w * 24 + 4 * j) * 64);
    }

    const int tc8 = (tid & 7) * 8;
    const int trr = tid >> 3;   // 0..31
    float lv0[9], lv1[9]; int li0[9], li1[9];
#pragma unroll
    for (int k = 0; k < 9; ++k) {
        lv0[k] = FLTMAX; li0[k] = 0x7fffffff;
        lv1[k] = FLTMAX; li1[k] = 0x7fffffff;
    }
    float vmax0 = FLTMAX, vmax1 = FLTMAX;
    int smax0 = 0, smax1 = 0;

    for (int t = s; t < 49; t += 8) {
        const int m0 = t * 64;
        float acc0[8], acc1[8];
#pragma unroll
        for (int j = 0; j < 8; ++j) { acc0[j] = 0.f; acc1[j] = 0.f; }

        __syncthreads();   // hm free for overwrite (and hn ready on first iter)
        {   // stage channels [0,48) of col tile
            const float* g = hb + (size_t)(w * 12 + lrow) * NN + m0 + lcol;
#pragma unroll
            for (int j = 0; j < 3; ++j)
                gload_lds16(g + (size_t)(4 * j) * NN, hm + (w * 12 + 4 * j) * 64);
        }
        __syncthreads();
#pragma unroll 4
        for (int c = 0; c < 48; ++c) {
            float2 av = *(const float2*)&hn[c * 64 + trr * 2];
            float4 b0 = *(const float4*)&hm[c * 64 + tc8];
            float4 b1 = *(const float4*)&hm[c * 64 + tc8 + 4];
            float bb[8] = {b0.x, b0.y, b0.z, b0.w, b1.x, b1.y, b1.z, b1.w};
#pragma unroll
            for (int j = 0; j < 8; ++j) {
                acc0[j] = fmaf(av.x, bb[j], acc0[j]);
                acc1[j] = fmaf(av.y, bb[j], acc1[j]);
            }
        }
        __syncthreads();
        {   // stage channels [48,96)
            const float* g = hb + (size_t)(48 + w * 12 + lrow) * NN + m0 + lcol;
#pragma unroll
            for (int j = 0; j < 3; ++j)
                gload_lds16(g + (size_t)(4 * j) * NN, hm + (w * 12 + 4 * j) * 64);
        }
        __syncthreads();
#pragma unroll 4
        for (int c = 0; c < 48; ++c) {
            float2 av = *(const float2*)&hn[(48 + c) * 64 + trr * 2];
            float4 b0 = *(const float4*)&hm[c * 64 + tc8];
            float4 b1 = *(const float4*)&hm[c * 64 + tc8 + 4];
            float bb[8] = {b0.x, b0.y, b0.z, b0.w, b1.x, b1.y, b1.z, b1.w};
#pragma unroll
            for (int j = 0; j < 8; ++j) {
                acc0[j] = fmaf(av.x, bb[j], acc0[j]);
                acc1[j] = fmaf(av.y, bb[j], acc1[j]);
            }
        }
        // score + in-register top-9 insert
        float4 xa = *(const float4*)&x2[(size_t)b * NN + m0 + tc8];
        float4 xc = *(const float4*)&x2[(size_t)b * NN + m0 + tc8 + 4];
        float xs[8] = {xa.x, xa.y, xa.z, xa.w, xc.x, xc.y, xc.z, xc.w};
#pragma unroll
        for (int j = 0; j < 8; ++j) {
            float v0 = fmaf(-2.f, acc0[j], xs[j]);
            if (v0 < vmax0) {
                int m = m0 + tc8 + j;
#pragma unroll
                for (int k = 0; k < 9; ++k) if (k == smax0) { lv0[k] = v0; li0[k] = m; }
                vmax0 = lv0[0]; smax0 = 0;
#pragma unroll
                for (int k = 1; k < 9; ++k) if (lv0[k] > vmax0) { vmax0 = lv0[k]; smax0 = k; }
            }
            float v1 = fmaf(-2.f, acc1[j], xs[j]);
            if (v1 < vmax1) {
                int m = m0 + tc8 + j;
#pragma unroll
                for (int k = 0; k < 9; ++k) if (k == smax1) { lv1[k] = v1; li1[k] = m; }
                vmax1 = lv1[0]; smax1 = 0;
#pragma unroll
                for (int k = 1; k < 9; ++k) if (lv1[k] > vmax1) { vmax1 = lv1[k]; smax1 = k; }
            }
        }
    }

    // -------- merge: overlay smem with [64 rows][8 slices][9] (val,idx) ------
    __syncthreads();
    float* mv = smem;                 // 4608 floats
    int*   mi = (int*)(smem + 4608);  // 4608 ints
    {
        const int r0 = trr * 2, sl = tid & 7;
#pragma unroll
        for (int k = 0; k < 9; ++k) {
            mv[(r0 * 8 + sl) * 9 + k] = lv0[k];       mi[(r0 * 8 + sl) * 9 + k] = li0[k];
            mv[((r0 + 1) * 8 + sl) * 9 + k] = lv1[k]; mi[((r0 + 1) * 8 + sl) * 9 + k] = li1[k];
        }
    }
    __syncthreads();
    if (tid < 128) {   // stage 1: partial selection-sort of 9 from 36 (in place)
        const int row = tid >> 1, q = tid & 1;
        const int base = (row * 8 + q * 4) * 9;
        for (int kk = 0; kk < 9; ++kk) {
            float bv = mv[base + kk]; int bi2 = mi[base + kk]; int bs = kk;
            for (int j = kk + 1; j < 36; ++j) {
                float v = mv[base + j]; int ii = mi[base + j];
                if (v < bv || (v == bv && ii < bi2)) { bv = v; bi2 = ii; bs = j; }
            }
            mv[base + bs] = mv[base + kk]; mi[base + bs] = mi[base + kk];
            mv[base + kk] = bv;            mi[base + kk] = bi2;
        }
    }
    __syncthreads();
    if (tid < 64) {    // stage 2: merge two sorted 9-lists -> global top-9
        const int row = tid;
        const int b0 = (row * 8) * 9, b1 = (row * 8 + 4) * 9;
        const size_t gbase = (size_t)b * NN + n0 + row;
        for (int kk = 0; kk < 9; ++kk) {
            float bv = FLTMAX; int bi2 = 0x7fffffff; int bs = 0, bl = 0;
            for (int j = 0; j < 9; ++j) {
                float v = mv[b0 + j]; int ii = mi[b0 + j];
                if (v < bv || (v == bv && ii < bi2)) { bv = v; bi2 = ii; bs = j; bl = 0; }
            }
            for (int j = 0; j < 9; ++j) {
                float v = mv[b1 + j]; int ii = mi[b1 + j];
                if (v < bv || (v == bv && ii < bi2)) { bv = v; bi2 = ii; bs = j; bl = 1; }
            }
            mv[(bl ? b1 : b0) + bs] = FLTMAX;
            cand_val[(size_t)(s * 9 + kk) * (BB * NN) + gbase] = bv;
            cand_idx[(size_t)(s * 9 + kk) * (BB * NN) + gbase] = bi2;
        }
    }
}

// ---------------- K4: merge 8 splits -> idx9 ---------------------------------
__global__ __launch_bounds__(256) void k_merge(const float* __restrict__ cand_val,
                                               const int* __restrict__ cand_idx,
                                               int* __restrict__ idx9) {
    int gid = blockIdx.x * 256 + threadIdx.x;   // exactly B*N
    float vals[9]; int inds[9];
#pragma unroll
    for (int k = 0; k < 9; ++k) { vals[k] = FLTMAX; inds[k] = 0x7fffffff; }
    float vmax = FLTMAX; int smax = 0;
    for (int j = 0; j < 72; ++j) {
        float v = cand_val[(size_t)j * (BB * NN) + gid];
        int ii = cand_idx[(size_t)j * (BB * NN) + gid];
        if (v < vmax) {
#pragma unroll
            for (int k = 0; k < 9; ++k)
                if (k == smax) { vals[k] = v; inds[k] = ii; }
            vmax = vals[0]; smax = 0;
#pragma unroll
            for (int k = 1; k < 9; ++k)
                if (vals[k] > vmax) { vmax = vals[k]; smax = k; }
        }
    }
#pragma unroll
    for (int k = 0; k < 9; ++k) idx9[(size_t)gid * 9 + k] = inds[k];
}

// ---------------- K5: [U;V] @ h -> acT (b,n,384); weight transform fused -----
__global__ __launch_bounds__(256) void k_ac(const float* __restrict__ h, const float* __restrict__ gw,
                                            const float* __restrict__ gb, float* __restrict__ acT) {
    __shared__ float sm[96 * 98 + 96 * 64];
    float* wT = sm;
    float* hl = sm + 96 * 98;
    const int tid = threadIdx.x;
    const int n0 = blockIdx.x * 64, ot = blockIdx.y, b = blockIdx.z;
    // rows 0..191 of M = W1 - W2, rows 192..383 = W2  (W=[W1|W2], 192x192)
    for (int i = tid; i < 96 * 96; i += 256) {
        int o = i / 96, c = i - o * 96;
        float v;
        if (ot < 2) {
            const float* gwp = gw + (size_t)(ot * 96 + o) * 192;
            v = gwp[c] - gwp[96 + c];
        } else {
            v = gw[(size_t)((ot - 2) * 96 + o) * 192 + 96 + c];
        }
        wT[c * 98 + o] = v;
    }
    const float* hb = h + (size_t)b * CC * NN;
    for (int i = tid; i < 96 * 64; i += 256) {
        int c = i >> 6, nl = i & 63;
        hl[i] = hb[(size_t)c * NN + n0 + nl];
    }
    __syncthreads();
    const int tr = tid >> 4, tc = tid & 15;
    float acc[6][4];
#pragma unroll
    for (int i = 0; i < 6; ++i)
#pragma unroll
        for (int j = 0; j < 4; ++j) acc[i][j] = 0.f;
#pragma unroll 4
    for (int c = 0; c < 96; ++c) {
        float4 xv = *(const float4*)&hl[c * 64 + tc * 4];
        const float* wp = &wT[c * 98 + tr * 6];
        float2 w01 = *(const float2*)(wp);
        float2 w23 = *(const float2*)(wp + 2);
        float2 w45 = *(const float2*)(wp + 4);
        float wv[6] = {w01.x, w01.y, w23.x, w23.y, w45.x, w45.y};
        float xj[4] = {xv.x, xv.y, xv.z, xv.w};
#pragma unroll
        for (int i = 0; i < 6; ++i)
#pragma unroll
            for (int j = 0; j < 4; ++j) acc[i][j] = fmaf(wv[i], xj[j], acc[i][j]);
    }
    const int obase = ot * 96 + tr * 6;
    float bs[6];
#pragma unroll
    for (int i = 0; i < 6; ++i) bs[i] = (ot < 2) ? gb[obase + i] : 0.f;
#pragma unroll
    for (int j = 0; j < 4; ++j) {
        float* dst = acT + ((size_t)b * NN + n0 + tc * 4 + j) * 384 + obase;
        *(float2*)(dst + 0) = make_float2(acc[0][j] + bs[0], acc[1][j] + bs[1]);
        *(float2*)(dst + 2) = make_float2(acc[2][j] + bs[2], acc[3][j] + bs[3]);
        *(float2*)(dst + 4) = make_float2(acc[4][j] + bs[4], acc[5][j] + bs[5]);
    }
}

// ---------------- K6: gather neighbors, k-max, relu -> gT (b,n,192) ----------
__global__ __launch_bounds__(64) void k_gather(const float* __restrict__ acT, const int* __restrict__ idx9,
                                               float* __restrict__ gT) {
    const int lane = threadIdx.x;
    const int b = blockIdx.y;
    const int nb = blockIdx.x * 4;
    for (int r = 0; r < 4; ++r) {
        const int n = nb + r;
        const float* ar = acT + ((size_t)b * NN + n) * 384;
        float a0 = ar[lane], a1 = ar[lane + 64], a2 = ar[lane + 128];
        const int* ip = idx9 + ((size_t)b * NN + n) * 9;
        int jj[9];
#pragma unroll
        for (int k = 0; k < 9; ++k) jj[k] = ip[k];
        float m0 = -FLTMAX, m1 = -FLTMAX, m2 = -FLTMAX;
#pragma unroll
        for (int k = 0; k < 9; ++k) {
            const float* cr = acT + ((size_t)b * NN + jj[k]) * 384 + 192;
            m0 = fmaxf(m0, a0 + cr[lane]);
            m1 = fmaxf(m1, a1 + cr[lane + 64]);
            m2 = fmaxf(m2, a2 + cr[lane + 128]);
        }
        float* gr = gT + ((size_t)b * NN + n) * 192;
        gr[lane] = fmaxf(m0, 0.f);
        gr[lane + 64] = fmaxf(m1, 0.f);
        gr[lane + 128] = fmaxf(m2, 0.f);
    }
}

// ---------------- K7: fc2 (NT gemm) -> out, fused channel mean/max -----------
__global__ __launch_bounds__(256) void k_fc2(const float* __restrict__ gT, const float* __restrict__ w,
                                             const float* __restrict__ bias, float* __restrict__ out,
                                             float* __restrict__ sa_in) {
    __shared__ float Wc[96 * 36];
    __shared__ float Gc[64 * 36];
    const int tid = threadIdx.x;
    const int n0 = blockIdx.x * 64, b = blockIdx.y;
    const int tr = tid >> 4, tc = tid & 15;
    float acc[6][4];
#pragma unroll
    for (int i = 0; i < 6; ++i)
#pragma unroll
        for (int j = 0; j < 4; ++j) acc[i][j] = 0.f;
    for (int kc = 0; kc < 192; kc += 32) {
        for (int i = tid; i < 96 * 32; i += 256) {
            int c = i >> 5, k = i & 31;
            Wc[c * 36 + k] = w[(size_t)c * 192 + kc + k];
        }
        for (int i = tid; i < 64 * 32; i += 256) {
            int nl = i >> 5, k = i & 31;
            Gc[nl * 36 + k] = gT[((size_t)b * NN + n0 + nl) * 192 + kc + k];
        }
        __syncthreads();
#pragma unroll
        for (int k = 0; k < 32; k += 4) {
            float4 wv[6]; float4 gv[4];
#pragma unroll
            for (int i = 0; i < 6; ++i) wv[i] = *(const float4*)&Wc[(tr * 6 + i) * 36 + k];
#pragma unroll
            for (int j = 0; j < 4; ++j) gv[j] = *(const float4*)&Gc[(tc * 4 + j) * 36 + k];
#pragma unroll
            for (int i = 0; i < 6; ++i)
#pragma unroll
                for (int j = 0; j < 4; ++j) {
                    acc[i][j] = fmaf(wv[i].x, gv[j].x, acc[i][j]);
                    acc[i][j] = fmaf(wv[i].y, gv[j].y, acc[i][j]);
                    acc[i][j] = fmaf(wv[i].z, gv[j].z, acc[i][j]);
                    acc[i][j] = fmaf(wv[i].w, gv[j].w, acc[i][j]);
                }
        }
        __syncthreads();
    }
    float* ob = out + (size_t)b * CC * NN;
    float bs[6];
#pragma unroll
    for (int i = 0; i < 6; ++i) bs[i] = bias[tr * 6 + i];
    float ps[4], pm[4];
#pragma unroll
    for (int j = 0; j < 4; ++j) { ps[j] = 0.f; pm[j] = -FLTMAX; }
#pragma unroll
    for (int i = 0; i < 6; ++i) {
        float o0 = acc[i][0] + bs[i], o1 = acc[i][1] + bs[i];
        float o2 = acc[i][2] + bs[i], o3 = acc[i][3] + bs[i];
        *(float4*)&ob[(size_t)(tr * 6 + i) * NN + n0 + tc * 4] = make_float4(o0, o1, o2, o3);
        ps[0] += o0; ps[1] += o1; ps[2] += o2; ps[3] += o3;
        pm[0] = fmaxf(pm[0], o0); pm[1] = fmaxf(pm[1], o1);
        pm[2] = fmaxf(pm[2], o2); pm[3] = fmaxf(pm[3], o3);
    }
    // channel mean/max reduction across tr (16 groups of 6 channels)
    float* red  = Wc;          // [16][64]
    float* red2 = Wc + 1024;   // [16][64]
#pragma unroll
    for (int j = 0; j < 4; ++j) {
        red[tr * 64 + tc * 4 + j]  = ps[j];
        red2[tr * 64 + tc * 4 + j] = pm[j];
    }
    __syncthreads();
    if (tid < 64) {
        float s_ = 0.f, m_ = -FLTMAX;
#pragma unroll
        for (int t = 0; t < 16; ++t) { s_ += red[t * 64 + tid]; m_ = fmaxf(m_, red2[t * 64 + tid]); }
        sa_in[(size_t)b * 2 * NN + n0 + tid] = s_ * (1.0f / 96.0f);
        sa_in[(size_t)b * 2 * NN + NN + n0 + tid] = m_;
    }
}

// ---------------- K9: 7x7 conv + sigmoid + out*att + shortcut (in place) -----
__global__ __launch_bounds__(256) void k_att(const float* __restrict__ sa_in, const float* __restrict__ sw,
                                             const float* __restrict__ x, float* __restrict__ out) {
    int n = blockIdx.x * 256 + threadIdx.x;
    int b = blockIdx.y;
    if (n >= NN) return;
    int y = n / 56, xw = n - y * 56;
    float acc = 0.f;
#pragma unroll
    for (int ci = 0; ci < 2; ++ci) {
        const float* sb = sa_in + ((size_t)b * 2 + ci) * NN;
#pragma unroll
        for (int dy = 0; dy < 7; ++dy) {
            int yy = y + dy - 3;
            if ((unsigned)yy < 56u) {
#pragma unroll
                for (int dx = 0; dx < 7; ++dx) {
                    int xx = xw + dx - 3;
                    if ((unsigned)xx < 56u)
                        acc = fmaf(sb[yy * 56 + xx], sw[(ci * 7 + dy) * 7 + dx], acc);
                }
            }
        }
    }
    float att = 1.f / (1.f + expf(-acc));
    const float* xb = x + (size_t)b * CC * NN + n;
    float* ob = out + (size_t)b * CC * NN + n;
#pragma unroll 4
    for (int c = 0; c < 96; ++c) {
        size_t o = (size_t)c * NN;
        ob[o] = fmaf(ob[o], att, xb[o]);
    }
}

extern "C" void kernel_launch(void* const* d_in, const int* in_sizes, int n_in,
                              void* d_out, int out_size, void* d_ws, size_t ws_size,
                              hipStream_t stream) {
    (void)in_sizes; (void)n_in; (void)out_size; (void)ws_size;
    const float* x       = (const float*)d_in[0];
    const float* fc1_w   = (const float*)d_in[1];
    const float* fc1_b   = (const float*)d_in[2];
    const float* gconv_w = (const float*)d_in[3];
    const float* gconv_b = (const float*)d_in[4];
    const float* fc2_w   = (const float*)d_in[5];
    const float* fc2_b   = (const float*)d_in[6];
    const float* sa_w    = (const float*)d_in[7];
    float* out = (float*)d_out;

    // workspace layout (floats); cand_* alias gT region (disjoint lifetimes)
    float* ws   = (float*)d_ws;
    float* h    = ws;                                   // 1,204,224
    float* x2   = h + (size_t)BB * CC * NN;             // 12,544
    int*   idx9 = (int*)(x2 + BB * NN);                 // 112,896 ints
    float* acT  = (float*)(idx9 + (size_t)BB * NN * 9); // 4,816,896
    float* gT   = acT + (size_t)BB * NN * 384;          // 2,408,448
    float* cand_val = gT;                               // 903,168 (aliases gT)
    int*   cand_idx = (int*)(cand_val + (size_t)72 * BB * NN);
    float* sa_in = gT + (size_t)BB * NN * 192;          // 25,088

    k_fc1   <<<dim3(49, BB), 256, 0, stream>>>(x, fc1_w, fc1_b, h, x2);
    k_dist  <<<dim3(49, 8, BB), 256, 0, stream>>>(h, x2, cand_val, cand_idx);
    k_merge <<<dim3(49), 256, 0, stream>>>(cand_val, cand_idx, idx9);
    k_ac    <<<dim3(49, 4, BB), 256, 0, stream>>>(h, gconv_w, gconv_b, acT);
    k_gather<<<dim3(784, BB), 64, 0, stream>>>(acT, idx9, gT);
    k_fc2   <<<dim3(49, BB), 256, 0, stream>>>(gT, fc2_w, fc2_b, out, sa_in);
    k_att   <<<dim3(13, BB), 256, 0, stream>>>(sa_in, sa_w, x, out);
}